// Round 4
// baseline (279.236 us; speedup 1.0000x reference)
//
#include <hip/hip_runtime.h>
#include <hip/hip_cooperative_groups.h>

namespace cg = cooperative_groups;

#define NROW 512
#define NCOL 65536
#define BANDS 8

static __device__ __forceinline__ float wave_sum(float x) {
  #pragma unroll
  for (int off = 32; off; off >>= 1) x += __shfl_down(x, off, 64);
  return x;
}

// async global->LDS, 16 bytes per lane (global_load_lds_dwordx4).
// LDS dest is wave-uniform base + lane*16; global src is per-lane.
static __device__ __forceinline__ void async_copy16(const float* g, float* l) {
  __builtin_amdgcn_global_load_lds(
      (const __attribute__((address_space(1))) unsigned int*)g,
      (__attribute__((address_space(3))) unsigned int*)l, 16, 0, 0);
}

// ---- k1: partial colsums of E = exp(-20M), LDS-staged ----------------------
// 2048 blocks x 256 thr. Block (band, colblk): rows [band*64,+64), cols
// [colblk*256,+256). 4 tiles of 16 rows, double-buffered via global_load_lds.
// Wave w stages tile rows 4w..4w+3 (1 KB each); thread consumes 4 rows x 4 cols.
__global__ __launch_bounds__(256)
void k1_colsum(const float* __restrict__ M, float* __restrict__ tPart,
               float* __restrict__ eA) {
  const int tid = threadIdx.x, bid = blockIdx.x;
  const int colblk = bid & 255, band = bid >> 8;
  const int lane = tid & 63, w = tid >> 6;
  const int col0 = colblk << 8;

  __shared__ float buf[2][16 * 256];   // 2 x 16 KB
  __shared__ float sCol[4 * 256];

  if (bid == 0 && tid < 8) eA[tid] = 0.f;  // [0]=err1 [1]=err51 [2]=loss [4]=cnt

  const float* Mb = M + (size_t)(band << 6) * NCOL + col0;

  // stage tile g into buf[b]: 4 issues/wave, one tile-row (1 KB) per issue
  #define STAGE_K1(g, b)                                                      \
    {                                                                         \
      const float* src = Mb + (size_t)((g) << 4) * NCOL;                      \
      _Pragma("unroll")                                                       \
      for (int j = 0; j < 4; ++j) {                                           \
        const int tr = (w << 2) + j;                                          \
        async_copy16(src + (size_t)tr * NCOL + (lane << 2),                   \
                     &buf[b][tr * 256]);                                      \
      }                                                                       \
    }

  float4 cs = {0.f, 0.f, 0.f, 0.f};
  STAGE_K1(0, 0);
  __syncthreads();
  #pragma unroll
  for (int g = 0; g < 4; ++g) {
    if (g < 3) STAGE_K1(g + 1, (g + 1) & 1);
    const float* tb = &buf[g & 1][0];
    #pragma unroll
    for (int r = 0; r < 4; ++r) {
      float4 m = *(const float4*)(tb + ((w << 2) + r) * 256 + (lane << 2));
      cs.x += __expf(-20.f * m.x);
      cs.y += __expf(-20.f * m.y);
      cs.z += __expf(-20.f * m.z);
      cs.w += __expf(-20.f * m.w);
    }
    __syncthreads();   // drains staged loads (vmcnt) + ds reads (lgkmcnt)
  }
  #undef STAGE_K1

  *(float4*)(sCol + w * 256 + (lane << 2)) = cs;
  __syncthreads();
  if (tid < 64) {
    float4 a = *(const float4*)(sCol + (tid << 2));
    float4 b = *(const float4*)(sCol + 256 + (tid << 2));
    float4 c = *(const float4*)(sCol + 512 + (tid << 2));
    float4 d = *(const float4*)(sCol + 768 + (tid << 2));
    float4 t = {a.x + b.x + c.x + d.x, a.y + b.y + c.y + d.y,
                a.z + b.z + c.z + d.z, a.w + b.w + c.w + d.w};
    *(float4*)(tPart + (size_t)band * NCOL + col0 + (tid << 2)) = t;
  }
}

// ---- k1b: v1 = b / (colsum/512 + eps) --------------------------------------
__global__ __launch_bounds__(256)
void k1b_v1(const float* __restrict__ tPart, float* __restrict__ v) {
  const int gid = blockIdx.x * 256 + threadIdx.x;
  const int col0 = gid << 2;
  const float am = 1.0f / NROW, bm = 1.0f / NCOL, EPSV = 1e-16f;
  float4 t = {0.f, 0.f, 0.f, 0.f};
  #pragma unroll
  for (int b = 0; b < BANDS; ++b) {
    float4 p = *(const float4*)(tPart + (size_t)b * NCOL + col0);
    t.x += p.x; t.y += p.y; t.z += p.z; t.w += p.w;
  }
  float4 vv = {bm / (t.x * am + EPSV), bm / (t.y * am + EPSV),
               bm / (t.z * am + EPSV), bm / (t.w * am + EPSV)};
  *(float4*)(v + col0) = vv;
}

// ---- k2: u1[row] = a / (E[row,:] . v + eps) (L3-warm, register path) -------
__global__ __launch_bounds__(512)
void k2_rowdot(const float* __restrict__ M, const float* __restrict__ v,
               float* __restrict__ u) {
  const int tid = threadIdx.x, row = blockIdx.x;
  const float am = 1.0f / NROW, EPSV = 1e-16f;
  const float4* M4 = (const float4*)M + (size_t)row * (NCOL / 4);
  const float4* V4 = (const float4*)v;
  __shared__ float sRed[8];

  float acc = 0.f;
  #pragma unroll 8
  for (int it = 0; it < NCOL / 4 / 512; ++it) {   // 32 iters
    const int c = (it << 9) + tid;
    float4 m = M4[c];
    float4 vv = V4[c];
    acc += __expf(-20.f * m.x) * vv.x + __expf(-20.f * m.y) * vv.y
         + __expf(-20.f * m.z) * vv.z + __expf(-20.f * m.w) * vv.w;
  }
  acc = wave_sum(acc);
  if ((tid & 63) == 0) sRed[tid >> 6] = acc;
  __syncthreads();
  if (tid == 0) {
    float s = 0.f;
    #pragma unroll
    for (int w = 0; w < 8; ++w) s += sRed[w];
    u[row] = am / (s + EPSV);
  }
}

// ---- k3: partial colsums of E^T u1 + fused loss, LDS-staged ----------------
// Same geometry as k1.
__global__ __launch_bounds__(256)
void k3_colsum_u(const float* __restrict__ M, const float* __restrict__ v,
                 const float* __restrict__ u, float* __restrict__ tPart,
                 float* __restrict__ eA) {
  const int tid = threadIdx.x, bid = blockIdx.x;
  const int colblk = bid & 255, band = bid >> 8;
  const int lane = tid & 63, w = tid >> 6;
  const int col0 = colblk << 8;

  __shared__ float buf[2][16 * 256];
  __shared__ float sCol[4 * 256];
  __shared__ float sU[64];
  __shared__ float sRed[4];

  if (tid < 64) sU[tid] = u[(band << 6) + tid];

  const float* Mb = M + (size_t)(band << 6) * NCOL + col0;
  const float4 vv = *(const float4*)(v + col0 + (lane << 2));

  #define STAGE_K3(g, b)                                                      \
    {                                                                         \
      const float* src = Mb + (size_t)((g) << 4) * NCOL;                      \
      _Pragma("unroll")                                                       \
      for (int j = 0; j < 4; ++j) {                                           \
        const int tr = (w << 2) + j;                                          \
        async_copy16(src + (size_t)tr * NCOL + (lane << 2),                   \
                     &buf[b][tr * 256]);                                      \
      }                                                                       \
    }

  float4 cs = {0.f, 0.f, 0.f, 0.f};
  float lacc = 0.f;
  STAGE_K3(0, 0);
  __syncthreads();
  #pragma unroll
  for (int g = 0; g < 4; ++g) {
    if (g < 3) STAGE_K3(g + 1, (g + 1) & 1);
    const float* tb = &buf[g & 1][0];
    #pragma unroll
    for (int r = 0; r < 4; ++r) {
      float4 m = *(const float4*)(tb + ((w << 2) + r) * 256 + (lane << 2));
      float e0 = __expf(-20.f * m.x), e1 = __expf(-20.f * m.y);
      float e2 = __expf(-20.f * m.z), e3 = __expf(-20.f * m.w);
      float us = sU[(g << 4) + (w << 2) + r];
      cs.x = fmaf(e0, us, cs.x);
      cs.y = fmaf(e1, us, cs.y);
      cs.z = fmaf(e2, us, cs.z);
      cs.w = fmaf(e3, us, cs.w);
      lacc += us * (e0 * m.x * vv.x + e1 * m.y * vv.y
                  + e2 * m.z * vv.z + e3 * m.w * vv.w);
    }
    __syncthreads();
  }
  #undef STAGE_K3

  *(float4*)(sCol + w * 256 + (lane << 2)) = cs;
  lacc = wave_sum(lacc);
  if ((tid & 63) == 0) sRed[tid >> 6] = lacc;
  __syncthreads();
  if (tid < 64) {
    float4 a = *(const float4*)(sCol + (tid << 2));
    float4 b = *(const float4*)(sCol + 256 + (tid << 2));
    float4 c = *(const float4*)(sCol + 512 + (tid << 2));
    float4 d = *(const float4*)(sCol + 768 + (tid << 2));
    float4 t = {a.x + b.x + c.x + d.x, a.y + b.y + c.y + d.y,
                a.z + b.z + c.z + d.z, a.w + b.w + c.w + d.w};
    *(float4*)(tPart + (size_t)band * NCOL + col0 + (tid << 2)) = t;
  }
  if (tid == 0)
    atomicAdd(&eA[2], sRed[0] + sRed[1] + sRed[2] + sRed[3]);
}

// ---- k3b: t = reduce(partials), tArr, err1, + last-block decide ------------
__global__ __launch_bounds__(256)
void k3b_err(const float* __restrict__ tPart, const float* __restrict__ v,
             float* __restrict__ tArr, float* __restrict__ eA,
             float* __restrict__ out, int* __restrict__ done) {
  const int tid = threadIdx.x;
  const int gid = blockIdx.x * 256 + tid;
  const int col0 = gid << 2;
  const float bm = 1.0f / NCOL;
  __shared__ float sRed[4];

  float4 t = {0.f, 0.f, 0.f, 0.f};
  #pragma unroll
  for (int b = 0; b < BANDS; ++b) {
    float4 p = *(const float4*)(tPart + (size_t)b * NCOL + col0);
    t.x += p.x; t.y += p.y; t.z += p.z; t.w += p.w;
  }
  *(float4*)(tArr + col0) = t;
  float4 vv = *(const float4*)(v + col0);
  float pe = fabsf(vv.x * t.x - bm) + fabsf(vv.y * t.y - bm)
           + fabsf(vv.z * t.z - bm) + fabsf(vv.w * t.w - bm);
  pe = wave_sum(pe);
  if ((tid & 63) == 0) sRed[tid >> 6] = pe;
  __syncthreads();
  if (tid == 0) {
    atomicAdd(&eA[0], sRed[0] + sRed[1] + sRed[2] + sRed[3]);
    __threadfence();
    int old = atomicAdd((int*)(eA + 4), 1);
    if (old == (int)gridDim.x - 1) {      // last block: decide
      __threadfence();
      float err = atomicAdd(&eA[0], 0.f);
      float ls  = atomicAdd(&eA[2], 0.f);
      if (err <= 0.005f) { out[0] = 100.f * ls; done[0] = 1; }
      else               { out[0] = 0.f;        done[0] = 0; }
    }
  }
}

// ---- k5: cooperative fallback (iters 2..100 + loss); exits when done -------
__global__ __launch_bounds__(1024)
void k5_fallback(const float* __restrict__ M, float* __restrict__ out,
                 float* __restrict__ v, float* __restrict__ u,
                 const float* __restrict__ tArr, float* __restrict__ eA,
                 const int* __restrict__ done) {
  if (done[0]) return;
  cg::grid_group grid = cg::this_grid();
  const int tid = threadIdx.x, bid = blockIdx.x;
  const float am = 1.0f / NROW, bm = 1.0f / NCOL, EPSV = 1e-16f;

  __shared__ float sU[NROW];
  __shared__ float sCol[16 * 256];
  __shared__ float sRedA[16], sRedB[16];

  const int chunk = tid & 63;
  const int part  = tid >> 6;
  const int col0  = (bid << 8) + (chunk << 2);
  const int r0    = part << 5;
  const int row0  = bid << 1;

  float tt = (tid < 256) ? tArr[(bid << 8) + tid] : 0.f;

  int cpt = 1;
  while (true) {
    if (tid < 256) v[(bid << 8) + tid] = bm / (tt + EPSV);
    grid.sync();
    cpt++;

    {
      const float4* M40 = (const float4*)M + (size_t)row0 * (NCOL / 4);
      const float4* M41 = (const float4*)M + (size_t)(row0 + 1) * (NCOL / 4);
      const float4* V4  = (const float4*)v;
      float ra = 0.f, rb = 0.f;
      #pragma unroll 4
      for (int it = 0; it < NCOL / 4 / 1024; ++it) {
        const int c = (it << 10) + tid;
        float4 vv = V4[c];
        float4 m0 = M40[c], m1 = M41[c];
        ra += __expf(-20.f * m0.x) * vv.x + __expf(-20.f * m0.y) * vv.y
            + __expf(-20.f * m0.z) * vv.z + __expf(-20.f * m0.w) * vv.w;
        rb += __expf(-20.f * m1.x) * vv.x + __expf(-20.f * m1.y) * vv.y
            + __expf(-20.f * m1.z) * vv.z + __expf(-20.f * m1.w) * vv.w;
      }
      ra = wave_sum(ra); rb = wave_sum(rb);
      if ((tid & 63) == 0) { sRedA[tid >> 6] = ra; sRedB[tid >> 6] = rb; }
      __syncthreads();
      if (tid < 2) {
        const float* sr = (tid == 0) ? sRedA : sRedB;
        float s = 0.f;
        #pragma unroll
        for (int w = 0; w < 16; ++w) s += sr[w];
        u[row0 + tid] = am / (s + EPSV);
      }
    }
    grid.sync();
    if (cpt >= 100) break;

    if (tid < NROW) sU[tid] = u[tid];
    __syncthreads();
    float4 cs = {0.f, 0.f, 0.f, 0.f};
    #pragma unroll 4
    for (int r = r0; r < r0 + 32; ++r) {
      float4 m = *(const float4*)(M + (size_t)r * NCOL + col0);
      float us = sU[r];
      cs.x = fmaf(__expf(-20.f * m.x), us, cs.x);
      cs.y = fmaf(__expf(-20.f * m.y), us, cs.y);
      cs.z = fmaf(__expf(-20.f * m.z), us, cs.z);
      cs.w = fmaf(__expf(-20.f * m.w), us, cs.w);
    }
    *(float4*)(sCol + part * 256 + (chunk << 2)) = cs;
    __syncthreads();
    if (tid < 256) {
      tt = 0.f;
      #pragma unroll
      for (int p = 0; p < 16; ++p) tt += sCol[p * 256 + tid];
    }

    if (cpt == 51) {
      float pe = (tid < 256) ? fabsf(v[(bid << 8) + tid] * tt - bm) : 0.f;
      pe = wave_sum(pe);
      __syncthreads();
      if ((tid & 63) == 0) sRedA[tid >> 6] = pe;
      __syncthreads();
      if (tid == 0) {
        float s = 0.f;
        #pragma unroll
        for (int w = 0; w < 16; ++w) s += sRedA[w];
        atomicAdd(&eA[1], s);
      }
      grid.sync();
      if (eA[1] <= 0.005f) break;
    }
  }

  __syncthreads();
  if (tid < NROW) sU[tid] = u[tid];
  __syncthreads();
  {
    const float4 vv = *(const float4*)(v + col0);
    float lacc = 0.f;
    #pragma unroll 4
    for (int r = r0; r < r0 + 32; ++r) {
      float4 m = *(const float4*)(M + (size_t)r * NCOL + col0);
      float us = sU[r];
      lacc += us * (__expf(-20.f * m.x) * m.x * vv.x
                  + __expf(-20.f * m.y) * m.y * vv.y
                  + __expf(-20.f * m.z) * m.z * vv.z
                  + __expf(-20.f * m.w) * m.w * vv.w);
    }
    lacc = wave_sum(lacc);
    if ((tid & 63) == 0) sRedA[tid >> 6] = lacc;
    __syncthreads();
    if (tid == 0) {
      float s = 0.f;
      #pragma unroll
      for (int w = 0; w < 16; ++w) s += sRedA[w];
      atomicAdd(out, 100.f * s);
    }
  }
}

extern "C" void kernel_launch(void* const* d_in, const int* in_sizes, int n_in,
                              void* d_out, int out_size, void* d_ws, size_t ws_size,
                              hipStream_t stream) {
  const float* M = (const float*)d_in[0];
  float* out = (float*)d_out;

  // ws: v | tArr | u | eA(+cnt) | done | tPart
  const size_t offV = 0;
  const size_t offT = offV + (size_t)NCOL * sizeof(float);      // 256 KB
  const size_t offU = offT + (size_t)NCOL * sizeof(float);      // 256 KB
  const size_t offE = offU + 4096;
  const size_t offD = offE + 256;
  const size_t offP = offD + 256;
  const size_t need = offP + (size_t)BANDS * NCOL * sizeof(float); // +2 MB
  if (ws_size < need) return;

  char* ws = (char*)d_ws;
  float* v     = (float*)(ws + offV);
  float* tArr  = (float*)(ws + offT);
  float* u     = (float*)(ws + offU);
  float* eA    = (float*)(ws + offE);
  int*   done  = (int*)(ws + offD);
  float* tPart = (float*)(ws + offP);

  k1_colsum  <<<dim3(2048), dim3(256), 0, stream>>>(M, tPart, eA);
  k1b_v1     <<<dim3(64),   dim3(256), 0, stream>>>(tPart, v);
  k2_rowdot  <<<dim3(512),  dim3(512), 0, stream>>>(M, v, u);
  k3_colsum_u<<<dim3(2048), dim3(256), 0, stream>>>(M, v, u, tPart, eA);
  k3b_err    <<<dim3(64),   dim3(256), 0, stream>>>(tPart, v, tArr, eA, out, done);

  void* args[] = { (void*)&M, (void*)&out, (void*)&v, (void*)&u,
                   (void*)&tArr, (void*)&eA, (void*)&done };
  hipLaunchCooperativeKernel((void*)k5_fallback, dim3(256), dim3(1024),
                             args, 0, stream);
}

// Round 6
// 252.645 us; speedup vs baseline: 1.1053x; 1.1053x over previous
//
#include <hip/hip_runtime.h>

#define NROW 512
#define NCOL 65536

static __device__ __forceinline__ float wave_sum(float x) {
  #pragma unroll
  for (int off = 32; off; off >>= 1) x += __shfl_down(x, off, 64);
  return x;
}

// Device-scope grid barrier (sense-reversal via monotone phase counter).
// Safe: grid = 256 blocks <= 256 CUs -> all blocks co-resident.
static __device__ __forceinline__ void gbar(int* cnt, int* phase) {
  __syncthreads();
  if (threadIdx.x == 0) {
    int ph = atomicAdd(phase, 0);                 // read phase BEFORE arriving
    __threadfence();                              // release prior writes
    if (atomicAdd(cnt, 1) == (int)gridDim.x - 1) {
      atomicExch(cnt, 0);
      __threadfence();
      atomicAdd(phase, 1);                        // release waiters
    } else {
      while (atomicAdd(phase, 0) == ph) { __builtin_amdgcn_s_sleep(8); }
    }
    __threadfence();                              // acquire
  }
  __syncthreads();
}

// ---- k1: v1 = b/(colsum(E)/512+eps) ---------------------------------------
// 512 blocks x 512 thr. Block owns 128 cols, all rows; thread 4 cols x 32 rows.
__global__ __launch_bounds__(512)
void k1_colsum(const float* __restrict__ M, float* __restrict__ v,
               float* __restrict__ eA, int* __restrict__ bar) {
  const int tid = threadIdx.x, bid = blockIdx.x;
  const int chunk = tid & 31;           // 32 float4 chunks = 128 cols
  const int part  = tid >> 5;           // 16 parts x 32 rows
  const int col0  = (bid << 7) + (chunk << 2);
  const int r0    = part << 5;
  const float am = 1.0f / NROW, bm = 1.0f / NCOL, EPSV = 1e-16f;

  __shared__ float sCol[16 * 128];

  if (bid == 0 && tid < 8) eA[tid] = 0.f;  // [0]=err1 [1]=err51 [2]=loss [4]=cnt
  if (bid == 0 && tid < 2) bar[tid] = 0;   // barrier cnt/phase

  const float* Mp = M + (size_t)r0 * NCOL + col0;
  float4 cs = {0.f, 0.f, 0.f, 0.f};
  #pragma unroll 8
  for (int rr = 0; rr < 32; ++rr) {
    float4 m = *(const float4*)(Mp + (size_t)rr * NCOL);
    cs.x += __expf(-20.f * m.x);
    cs.y += __expf(-20.f * m.y);
    cs.z += __expf(-20.f * m.z);
    cs.w += __expf(-20.f * m.w);
  }
  *(float4*)(sCol + part * 128 + (chunk << 2)) = cs;
  __syncthreads();
  if (tid < 128) {
    float t = 0.f;
    #pragma unroll
    for (int p = 0; p < 16; ++p) t += sCol[p * 128 + tid];
    v[(bid << 7) + tid] = bm / (t * am + EPSV);
  }
}

// ---- k2: u1[row] = a / (E[row,:] . v + eps) --------------------------------
__global__ __launch_bounds__(512)
void k2_rowdot(const float* __restrict__ M, const float* __restrict__ v,
               float* __restrict__ u) {
  const int tid = threadIdx.x, row = blockIdx.x;
  const float am = 1.0f / NROW, EPSV = 1e-16f;
  const float4* M4 = (const float4*)M + (size_t)row * (NCOL / 4);
  const float4* V4 = (const float4*)v;
  __shared__ float sRed[8];

  float acc = 0.f;
  #pragma unroll 8
  for (int it = 0; it < NCOL / 4 / 512; ++it) {   // 32 iters
    const int c = (it << 9) + tid;
    float4 m = M4[c];
    float4 vv = V4[c];
    acc += __expf(-20.f * m.x) * vv.x + __expf(-20.f * m.y) * vv.y
         + __expf(-20.f * m.z) * vv.z + __expf(-20.f * m.w) * vv.w;
  }
  acc = wave_sum(acc);
  if ((tid & 63) == 0) sRed[tid >> 6] = acc;
  __syncthreads();
  if (tid == 0) {
    float s = 0.f;
    #pragma unroll
    for (int w = 0; w < 8; ++w) s += sRed[w];
    u[row] = am / (s + EPSV);
  }
}

// ---- k3: t=colsum(E^T u1), err1, loss, tArr, + last-block decide ----------
__global__ __launch_bounds__(512)
void k3_colsum_u(const float* __restrict__ M, const float* __restrict__ v,
                 const float* __restrict__ u, float* __restrict__ tArr,
                 float* __restrict__ eA, float* __restrict__ out,
                 int* __restrict__ done) {
  const int tid = threadIdx.x, bid = blockIdx.x;
  const int chunk = tid & 31;
  const int part  = tid >> 5;
  const int col0  = (bid << 7) + (chunk << 2);
  const int r0    = part << 5;
  const float bm = 1.0f / NCOL;

  __shared__ float sU[NROW];
  __shared__ float sCol[16 * 128];
  __shared__ float sRed[8];

  sU[tid] = u[tid];                       // 512 threads == 512 rows
  __syncthreads();

  const float4 vv = *(const float4*)(v + col0);
  const float* Mp = M + (size_t)r0 * NCOL + col0;
  float4 cs = {0.f, 0.f, 0.f, 0.f};
  float lacc = 0.f;
  #pragma unroll 8
  for (int rr = 0; rr < 32; ++rr) {
    float4 m = *(const float4*)(Mp + (size_t)rr * NCOL);
    float e0 = __expf(-20.f * m.x), e1 = __expf(-20.f * m.y);
    float e2 = __expf(-20.f * m.z), e3 = __expf(-20.f * m.w);
    float us = sU[r0 + rr];
    cs.x = fmaf(e0, us, cs.x);
    cs.y = fmaf(e1, us, cs.y);
    cs.z = fmaf(e2, us, cs.z);
    cs.w = fmaf(e3, us, cs.w);
    lacc += us * (e0 * m.x * vv.x + e1 * m.y * vv.y
                + e2 * m.z * vv.z + e3 * m.w * vv.w);
  }
  *(float4*)(sCol + part * 128 + (chunk << 2)) = cs;
  lacc = wave_sum(lacc);
  if ((tid & 63) == 0) sRed[tid >> 6] = lacc;
  __syncthreads();

  float lblk = 0.f;
  if (tid == 0) {
    #pragma unroll
    for (int w = 0; w < 8; ++w) lblk += sRed[w];
  }
  float pe = 0.f;
  if (tid < 128) {
    float t = 0.f;
    #pragma unroll
    for (int p = 0; p < 16; ++p) t += sCol[p * 128 + tid];
    tArr[(bid << 7) + tid] = t;
    pe = fabsf(v[(bid << 7) + tid] * t - bm);
  }
  pe = wave_sum(pe);
  __syncthreads();                        // tid0 done reading sRed (loss)
  if ((tid & 63) == 0) sRed[tid >> 6] = pe;
  __syncthreads();
  if (tid == 0) {
    float es = 0.f;
    #pragma unroll
    for (int w = 0; w < 8; ++w) es += sRed[w];
    atomicAdd(&eA[0], es);
    atomicAdd(&eA[2], lblk);
    __threadfence();
    int old = atomicAdd((int*)(eA + 4), 1);
    if (old == (int)gridDim.x - 1) {      // last block: decide
      __threadfence();
      float err = atomicAdd(&eA[0], 0.f);
      float ls  = atomicAdd(&eA[2], 0.f);
      if (err <= 0.005f) { out[0] = 100.f * ls; done[0] = 1; }
      else               { out[0] = 0.f;        done[0] = 0; }
    }
  }
}

// ---- k5: persistent fallback, NORMAL launch + custom device barrier --------
// 256 blocks x 1024 thr (co-resident). Fast path: reads done[0]==1, returns.
__global__ __launch_bounds__(1024)
void k5_fallback(const float* __restrict__ M, float* __restrict__ out,
                 float* __restrict__ v, float* __restrict__ u,
                 const float* __restrict__ tArr, float* __restrict__ eA,
                 const int* __restrict__ done, int* __restrict__ bar) {
  if (done[0]) return;
  const int tid = threadIdx.x, bid = blockIdx.x;
  const float am = 1.0f / NROW, bm = 1.0f / NCOL, EPSV = 1e-16f;
  int* cnt = bar;
  int* phs = bar + 1;

  __shared__ float sU[NROW];
  __shared__ float sCol[16 * 256];
  __shared__ float sRedA[16], sRedB[16];
  __shared__ float sErr;

  const int chunk = tid & 63;
  const int part  = tid >> 6;
  const int col0  = (bid << 8) + (chunk << 2);
  const int r0    = part << 5;
  const int row0  = bid << 1;

  float tt = (tid < 256) ? tArr[(bid << 8) + tid] : 0.f;

  int cpt = 1;
  while (true) {
    if (tid < 256) v[(bid << 8) + tid] = bm / (tt + EPSV);
    gbar(cnt, phs);
    cpt++;

    {
      const float4* M40 = (const float4*)M + (size_t)row0 * (NCOL / 4);
      const float4* M41 = (const float4*)M + (size_t)(row0 + 1) * (NCOL / 4);
      const float4* V4  = (const float4*)v;
      float ra = 0.f, rb = 0.f;
      #pragma unroll 4
      for (int it = 0; it < NCOL / 4 / 1024; ++it) {
        const int c = (it << 10) + tid;
        float4 vv = V4[c];
        float4 m0 = M40[c], m1 = M41[c];
        ra += __expf(-20.f * m0.x) * vv.x + __expf(-20.f * m0.y) * vv.y
            + __expf(-20.f * m0.z) * vv.z + __expf(-20.f * m0.w) * vv.w;
        rb += __expf(-20.f * m1.x) * vv.x + __expf(-20.f * m1.y) * vv.y
            + __expf(-20.f * m1.z) * vv.z + __expf(-20.f * m1.w) * vv.w;
      }
      ra = wave_sum(ra); rb = wave_sum(rb);
      if ((tid & 63) == 0) { sRedA[tid >> 6] = ra; sRedB[tid >> 6] = rb; }
      __syncthreads();
      if (tid < 2) {
        const float* sr = (tid == 0) ? sRedA : sRedB;
        float s = 0.f;
        #pragma unroll
        for (int w = 0; w < 16; ++w) s += sr[w];
        u[row0 + tid] = am / (s + EPSV);
      }
    }
    gbar(cnt, phs);
    if (cpt >= 100) break;

    if (tid < NROW) sU[tid] = u[tid];
    __syncthreads();
    float4 cs = {0.f, 0.f, 0.f, 0.f};
    #pragma unroll 4
    for (int r = r0; r < r0 + 32; ++r) {
      float4 m = *(const float4*)(M + (size_t)r * NCOL + col0);
      float us = sU[r];
      cs.x = fmaf(__expf(-20.f * m.x), us, cs.x);
      cs.y = fmaf(__expf(-20.f * m.y), us, cs.y);
      cs.z = fmaf(__expf(-20.f * m.z), us, cs.z);
      cs.w = fmaf(__expf(-20.f * m.w), us, cs.w);
    }
    *(float4*)(sCol + part * 256 + (chunk << 2)) = cs;
    __syncthreads();
    if (tid < 256) {
      tt = 0.f;
      #pragma unroll
      for (int p = 0; p < 16; ++p) tt += sCol[p * 256 + tid];
    }

    if (cpt == 51) {
      float pe = (tid < 256) ? fabsf(v[(bid << 8) + tid] * tt - bm) : 0.f;
      pe = wave_sum(pe);
      __syncthreads();
      if ((tid & 63) == 0) sRedA[tid >> 6] = pe;
      __syncthreads();
      if (tid == 0) {
        float s = 0.f;
        #pragma unroll
        for (int w = 0; w < 16; ++w) s += sRedA[w];
        atomicAdd(&eA[1], s);
      }
      gbar(cnt, phs);
      if (tid == 0) sErr = atomicAdd(&eA[1], 0.f);
      __syncthreads();
      if (sErr <= 0.005f) break;
    }
  }

  __syncthreads();
  if (tid < NROW) sU[tid] = u[tid];
  __syncthreads();
  {
    const float4 vv = *(const float4*)(v + col0);
    float lacc = 0.f;
    #pragma unroll 4
    for (int r = r0; r < r0 + 32; ++r) {
      float4 m = *(const float4*)(M + (size_t)r * NCOL + col0);
      float us = sU[r];
      lacc += us * (__expf(-20.f * m.x) * m.x * vv.x
                  + __expf(-20.f * m.y) * m.y * vv.y
                  + __expf(-20.f * m.z) * m.z * vv.z
                  + __expf(-20.f * m.w) * m.w * vv.w);
    }
    lacc = wave_sum(lacc);
    if ((tid & 63) == 0) sRedA[tid >> 6] = lacc;
    __syncthreads();
    if (tid == 0) {
      float s = 0.f;
      #pragma unroll
      for (int w = 0; w < 16; ++w) s += sRedA[w];
      atomicAdd(out, 100.f * s);
    }
  }
}

extern "C" void kernel_launch(void* const* d_in, const int* in_sizes, int n_in,
                              void* d_out, int out_size, void* d_ws, size_t ws_size,
                              hipStream_t stream) {
  const float* M = (const float*)d_in[0];
  float* out = (float*)d_out;

  // ws: v | tArr | u | eA(+cnt) | done | bar
  const size_t offV = 0;
  const size_t offT = offV + (size_t)NCOL * sizeof(float);      // 256 KB
  const size_t offU = offT + (size_t)NCOL * sizeof(float);      // 256 KB
  const size_t offE = offU + 4096;
  const size_t offD = offE + 256;
  const size_t offB = offD + 256;
  const size_t need = offB + 256;
  if (ws_size < need) return;

  char* ws = (char*)d_ws;
  float* v    = (float*)(ws + offV);
  float* tArr = (float*)(ws + offT);
  float* u    = (float*)(ws + offU);
  float* eA   = (float*)(ws + offE);
  int*   done = (int*)(ws + offD);
  int*   bar  = (int*)(ws + offB);

  k1_colsum  <<<dim3(512), dim3(512), 0, stream>>>(M, v, eA, bar);
  k2_rowdot  <<<dim3(512), dim3(512), 0, stream>>>(M, v, u);
  k3_colsum_u<<<dim3(512), dim3(512), 0, stream>>>(M, v, u, tArr, eA, out, done);
  k5_fallback<<<dim3(256), dim3(1024), 0, stream>>>(M, out, v, u, tArr, eA,
                                                    done, bar);
}